// Round 5
// baseline (11818.468 us; speedup 1.0000x reference)
//
#include <hip/hip_runtime.h>
#include <math.h>

// SARABrainCore: 16-step spiking recurrent net, B=1024 T=16 D=1024 H=2048 O=1024.
// R3: inputs fp32, outputs fp32, internals fp64 (spike threshold is chaotic;
// fp64 tracks the fp64 ground truth; absmax 0.0039 vs fp32 JAX ref is spike
// flips from the reference's fp32 rounding, tolerance-accepted). fp32 GEMM is
// NOT safe: a single spike flip changes final attr by 1.0 >> 0.032 threshold.
// R4: GEMM moved to v_mfma_f64_16x16x4_f64 (78.6 TF matrix pipe).
// R5: HW-verified f64 MFMA C/D layout: row=(lane>>4)+4*reg, col=lane&15
// (regs stride 4 rows). R4's row=4*(lane>>4)+reg was an involution P off:
// readout passed (P twice cancels), raw rec/attr dumps failed. Keep this.
// R6/R7: 64x64 tile, 4 waves, BK=32 dbuf LDS, 1 barrier/K-tile, reg prefetch
// -> 2 blocks/CU: 548 -> 384 us, MfmaUtil 40 -> 60%.
// R8 (this round): remaining 40% MFMA idle = correlated stalls -- only 2
// barrier groups/CU, same-phase (both blocks prefetch+barrier in lockstep);
// Occupancy 21% showed only ~1.7 waves/SIMD. Decorrelate:
//   - 128-thread blocks (2 waves), tile 32(M)x64(N), each wave 32x32 (2x2
//     MFMA, same fragment reuse), BK=16 dbuf -> LDS 25KB.
//   - grid 1024 = 4 independent blocks/CU = 8 waves/CU, 2/SIMD from
//     DIFFERENT barrier groups -> stalls interleave instead of aligning.
//   - k ascending in steps of 4 unchanged -> bitwise-identical numerics.
// Fragment layouts (f64 16x16x4): A: row=lane&15, k=lane>>4;
// B: col=lane&15, k=lane>>4; C/D: col=lane&15, row=(lane>>4)+4*reg.

#define BB 1024
#define TT 16
#define DD 1024
#define HH 2048
#define OO 1024

typedef double d4 __attribute__((ext_vector_type(4)));

// ---- element readers ----
struct RdF {                               // fp32 input array
    const float* p; long ld;
    __device__ double operator()(int r, int c) const { return (double)p[(long)r*ld + c]; }
};
struct RdD {                               // fp64 internal array
    const double* p; long ld;
    __device__ double operator()(int r, int c) const { return p[(long)r*ld + c]; }
};
struct RdSum {                             // ctx + rec computed on the fly (exact)
    const double* a; const double* b; long ld;
    __device__ double operator()(int r, int c) const { long i=(long)r*ld+c; return a[i]+b[i]; }
};
struct RdSpk {                             // spike count -> mean (x0.0625 exact)
    const float* p; long ld;
    __device__ double operator()(int r, int c) const { return (double)p[(long)r*ld+c] * 0.0625; }
};

#define LDBS 66                  // Bs row stride in doubles (64 + 2 pad)
#define TILE_A (32*16)           // 512 doubles  (M=32 x BK=16, k-major)
#define TILE_B (16*LDBS)         // 1056 doubles (BK=16 x N=64+pad)
#define LDS_DBL (2*(TILE_A + TILE_B))   // 3136 doubles = 25.1 KB

// ---- fp64 MFMA GEMM core: 32(M)x64(N) tile, 128 thr (2 waves), BK=16,
// ---- double-buffered LDS, 1 barrier/K-tile, register prefetch. ----
// Wave w owns cols [w*32, w*32+32): 2x2 MFMA tiles of 16x16.
template<typename AR, typename BR>
__device__ __forceinline__ void gemm_mfma(AR A, BR B, int row0, int col0, int K,
                                          double* __restrict__ S,
                                          d4 acc[2][2])
{
    const int tid  = threadIdx.x;
    const int lane = tid & 63;
    const int wn   = tid >> 6;            // 0..1 (wave = N-half)
    const int l15  = lane & 15;
    const int l4   = lane >> 4;           // 0..3 = k within MFMA
    // A staging: 32 rows x 16 k, 4 elems/thread (k-contiguous global reads)
    const int am = tid >> 2, ak = (tid & 3) << 2;
    // B staging: 16 k x 64 cols, 8 elems/thread (col-contiguous global reads)
    const int bk = tid >> 3, bn = (tid & 7) << 3;

    double* A0 = S;
    double* B0 = S + TILE_A;
    double* A1 = S + TILE_A + TILE_B;
    double* B1 = A1 + TILE_A;

    double ar[4], br[8];
    #pragma unroll
    for (int j = 0; j < 4; ++j) ar[j] = A(row0 + am, ak + j);
    #pragma unroll
    for (int j = 0; j < 8; ++j) br[j] = B(bk, col0 + bn + j);

    __syncthreads();                      // prior users of S are done
    #pragma unroll
    for (int j = 0; j < 4; ++j) A0[(ak + j)*32 + am] = ar[j];
    #pragma unroll
    for (int j = 0; j < 8; ++j) B0[bk*LDBS + bn + j] = br[j];
    __syncthreads();

    double *cA = A0, *cB = B0, *nA = A1, *nB = B1;
    const int nt = K >> 4;
    for (int t = 0; t < nt; ++t) {
        if (t + 1 < nt) {                 // issue next-tile global loads early
            #pragma unroll
            for (int j = 0; j < 4; ++j) ar[j] = A(row0 + am, (t+1)*16 + ak + j);
            #pragma unroll
            for (int j = 0; j < 8; ++j) br[j] = B((t+1)*16 + bk, col0 + bn + j);
        }
        #pragma unroll
        for (int ks = 0; ks < 4; ++ks) {
            const int kk = ks*4 + l4;
            double a0 = cA[kk*32 +      l15];
            double a1 = cA[kk*32 + 16 + l15];
            double b0 = cB[kk*LDBS + wn*32 +      l15];
            double b1 = cB[kk*LDBS + wn*32 + 16 + l15];
            acc[0][0] = __builtin_amdgcn_mfma_f64_16x16x4f64(a0, b0, acc[0][0], 0, 0, 0);
            acc[0][1] = __builtin_amdgcn_mfma_f64_16x16x4f64(a0, b1, acc[0][1], 0, 0, 0);
            acc[1][0] = __builtin_amdgcn_mfma_f64_16x16x4f64(a1, b0, acc[1][0], 0, 0, 0);
            acc[1][1] = __builtin_amdgcn_mfma_f64_16x16x4f64(a1, b1, acc[1][1], 0, 0, 0);
        }
        if (t + 1 < nt) {                 // write-late into the other buffer
            #pragma unroll
            for (int j = 0; j < 4; ++j) nA[(ak + j)*32 + am] = ar[j];
            #pragma unroll
            for (int j = 0; j < 8; ++j) nB[bk*LDBS + bn + j] = br[j];
            __syncthreads();              // single barrier per K-tile
            double* x;
            x = cA; cA = nA; nA = x;
            x = cB; cB = nB; nB = x;
        }
    }
}

// Output element (i,j,r): row = row0 + i*16 + l4 + 4*r,        (HW-verified)
//                         col = col0 + wn*32 + j*16 + l15.
#define GEMM_EPILOG_VARS                                   \
    const int lane = threadIdx.x & 63;                     \
    const int wn   = threadIdx.x >> 6;                     \
    const int l15  = lane & 15, l4 = lane >> 4;

// ---- Wpf = Wp @ Wfc ----
__global__ __launch_bounds__(128) void k_wpf(const float* __restrict__ Wp,
                                             const float* __restrict__ Wfc,
                                             double* __restrict__ Wpf)
{
    __shared__ double S[LDS_DBL];
    d4 acc[2][2] = {};
    int row0 = blockIdx.y*32, col0 = blockIdx.x*64;
    gemm_mfma(RdF{Wp, HH}, RdF{Wfc, HH}, row0, col0, HH, S, acc);
    GEMM_EPILOG_VARS
    #pragma unroll
    for (int i=0;i<2;i++)
      #pragma unroll
      for (int j=0;j<2;j++)
        #pragma unroll
        for (int r=0;r<4;r++) {
            int d = row0 + i*16 + l4 + 4*r;
            int h = col0 + wn*32 + j*16 + l15;
            Wpf[(long)d*HH + h] = acc[i][j][r];
        }
}

// ---- bpf[h] = bp @ Wfc + bfc ----
__global__ __launch_bounds__(256) void k_bpf(const float* __restrict__ bp,
                                             const float* __restrict__ Wfc,
                                             const float* __restrict__ bfc,
                                             double* __restrict__ bpf)
{
    int h = blockIdx.x*256 + threadIdx.x;
    double acc = 0.0;
    for (int k = 0; k < HH; ++k)
        acc = fma((double)bp[k], (double)Wfc[(long)k*HH + h], acc);
    bpf[h] = acc + (double)bfc[h];
}

// ---- update = tanh(x_t @ Wpf + bpf); rec = BETA*rec + (1-BETA)*update ----
__global__ __launch_bounds__(128) void k_update(const float* __restrict__ x, int t,
                                                const double* __restrict__ Wpf,
                                                const double* __restrict__ bpf,
                                                double* __restrict__ rec)
{
    __shared__ double S[LDS_DBL];
    d4 acc[2][2] = {};
    int row0 = blockIdx.y*32, col0 = blockIdx.x*64;
    const float* x_t = x + (long)t*DD;              // row b at x[b*T*D + t*D]
    gemm_mfma(RdF{x_t, (long)TT*DD}, RdD{Wpf, HH}, row0, col0, DD, S, acc);
    GEMM_EPILOG_VARS
    const double BETA = 0.9;
    const double OMB  = 1.0 - BETA;   // Python fp64 semantics
    #pragma unroll
    for (int i=0;i<2;i++)
      #pragma unroll
      for (int j=0;j<2;j++)
        #pragma unroll
        for (int r=0;r<4;r++) {
            int b = row0 + i*16 + l4 + 4*r;
            int h = col0 + wn*32 + j*16 + l15;
            double u = tanh(acc[i][j][r] + bpf[h]);
            long idx = (long)b*HH + h;
            rec[idx] = BETA*rec[idx] + OMB*u;
        }
}

// ---- LayerNorm(rec) -> ctx  (one block per row) ----
__global__ __launch_bounds__(256) void k_ln(const double* __restrict__ rec,
                                            const float* __restrict__ gamma,
                                            const float* __restrict__ beta,
                                            double* __restrict__ ctx)
{
    __shared__ double red[256];
    int b = blockIdx.x, tid = threadIdx.x;
    const double* r = rec + (long)b*HH;
    double s = 0.0;
    for (int h = tid; h < HH; h += 256) s += r[h];
    red[tid] = s; __syncthreads();
    for (int off = 128; off > 0; off >>= 1) {
        if (tid < off) red[tid] += red[tid+off];
        __syncthreads();
    }
    double mean = red[0] / HH;
    __syncthreads();
    double v = 0.0;
    for (int h = tid; h < HH; h += 256) { double d = r[h]-mean; v += d*d; }
    red[tid] = v; __syncthreads();
    for (int off = 128; off > 0; off >>= 1) {
        if (tid < off) red[tid] += red[tid+off];
        __syncthreads();
    }
    double sd = sqrt(red[0] / HH + 1e-5);
    for (int h = tid; h < HH; h += 256) {
        long idx = (long)b*HH + h;
        ctx[idx] = (r[h]-mean)/sd * (double)gamma[h] + (double)beta[h];
    }
}

// ---- g = sigmoid((ctx+rec) @ Wg + bg); gated = g*ctx + (1-g)*rec ----
__global__ __launch_bounds__(128) void k_gate(const double* __restrict__ ctx,
                                              const double* __restrict__ rec,
                                              const float* __restrict__ Wg,
                                              const float* __restrict__ bg,
                                              double* __restrict__ gated)
{
    __shared__ double S[LDS_DBL];
    d4 acc[2][2] = {};
    int row0 = blockIdx.y*32, col0 = blockIdx.x*64;
    gemm_mfma(RdSum{ctx, rec, HH}, RdF{Wg, HH}, row0, col0, HH, S, acc);
    GEMM_EPILOG_VARS
    #pragma unroll
    for (int i=0;i<2;i++)
      #pragma unroll
      for (int j=0;j<2;j++)
        #pragma unroll
        for (int r=0;r<4;r++) {
            int b = row0 + i*16 + l4 + 4*r;
            int h = col0 + wn*32 + j*16 + l15;
            long idx = (long)b*HH + h;
            double g = 1.0/(1.0 + exp(-(acc[i][j][r] + (double)bg[h])));
            gated[idx] = g*ctx[idx] + (1.0-g)*rec[idx];
        }
}

// ---- current = gated@Wenc + attr@Wrec + benc + brec; LIF + spike count ----
__global__ __launch_bounds__(128) void k_current(const double* __restrict__ gated,
                                                 const float* __restrict__ Wenc,
                                                 const double* __restrict__ attr_in,
                                                 const float* __restrict__ Wrec,
                                                 const float* __restrict__ benc,
                                                 const float* __restrict__ brec,
                                                 double* __restrict__ attr_out,
                                                 float* __restrict__ spkcnt)
{
    __shared__ double S[LDS_DBL];
    d4 acc[2][2] = {};
    int row0 = blockIdx.y*32, col0 = blockIdx.x*64;
    gemm_mfma(RdD{gated,   HH}, RdF{Wenc, HH}, row0, col0, HH, S, acc);
    gemm_mfma(RdD{attr_in, HH}, RdF{Wrec, HH}, row0, col0, HH, S, acc);
    GEMM_EPILOG_VARS
    const double TAU = 2.0, THR = 1.0;
    #pragma unroll
    for (int i=0;i<2;i++)
      #pragma unroll
      for (int j=0;j<2;j++)
        #pragma unroll
        for (int r=0;r<4;r++) {
            int b = row0 + i*16 + l4 + 4*r;
            int h = col0 + wn*32 + j*16 + l15;
            long idx = (long)b*HH + h;
            double cur = acc[i][j][r] + (double)benc[h] + (double)brec[h];
            double a   = attr_in[idx];
            double nv  = a + (cur - a)/TAU;
            double sp  = (nv > THR) ? 1.0 : 0.0;
            attr_out[idx] = nv - sp*THR;
            spkcnt[idx] += (float)sp;
        }
}

// ---- out = (spkcnt/16) @ Wro + bro -> fp32 ----
__global__ __launch_bounds__(128) void k_readout(const float* __restrict__ spkcnt,
                                                 const float* __restrict__ Wro,
                                                 const float* __restrict__ bro,
                                                 float* __restrict__ out)
{
    __shared__ double S[LDS_DBL];
    d4 acc[2][2] = {};
    int row0 = blockIdx.y*32, col0 = blockIdx.x*64;
    gemm_mfma(RdSpk{spkcnt, HH}, RdF{Wro, OO}, row0, col0, HH, S, acc);
    GEMM_EPILOG_VARS
    #pragma unroll
    for (int i=0;i<2;i++)
      #pragma unroll
      for (int j=0;j<2;j++)
        #pragma unroll
        for (int r=0;r<4;r++) {
            int b = row0 + i*16 + l4 + 4*r;
            int o = col0 + wn*32 + j*16 + l15;
            out[(long)b*OO + o] = (float)(acc[i][j][r] + (double)bro[o]);
        }
}

__global__ __launch_bounds__(256) void k_d2f(const double* __restrict__ src,
                                             float* __restrict__ dst)
{
    long i = (long)blockIdx.x*256 + threadIdx.x;
    dst[i] = (float)src[i];
}

extern "C" void kernel_launch(void* const* d_in, const int* in_sizes, int n_in,
                              void* d_out, int out_size, void* d_ws, size_t ws_size,
                              hipStream_t stream) {
    const float* x    = (const float*)d_in[0];
    const float* Wp   = (const float*)d_in[1];
    const float* bp   = (const float*)d_in[2];
    const float* Wfc  = (const float*)d_in[3];
    const float* bfc  = (const float*)d_in[4];
    const float* gamma= (const float*)d_in[5];
    const float* beta = (const float*)d_in[6];
    const float* Wg   = (const float*)d_in[7];
    const float* bg   = (const float*)d_in[8];
    const float* Wenc = (const float*)d_in[9];
    const float* benc = (const float*)d_in[10];
    const float* Wrec = (const float*)d_in[11];
    const float* brec = (const float*)d_in[12];
    const float* Wro  = (const float*)d_in[13];
    const float* bro  = (const float*)d_in[14];
    float* out = (float*)d_out;

    const long NBH = (long)BB*HH;     // 2M elems
    char* p = (char*)d_ws;
    double* Wpf   = (double*)p; p += (long)DD*HH*sizeof(double);   // 16.8 MB
    double* bpf   = (double*)p; p += HH*sizeof(double);
    double* rec   = (double*)p; p += NBH*sizeof(double);           // 16.8 MB
    double* attrA = (double*)p; p += NBH*sizeof(double);           // 16.8 MB
    double* attrB = (double*)p; p += NBH*sizeof(double);           // 16.8 MB
    double* ctx   = (double*)p; p += NBH*sizeof(double);           // 16.8 MB
    double* gated = (double*)p; p += NBH*sizeof(double);           // 16.8 MB
    float*  spkcnt= (float*)p;  p += NBH*sizeof(float);            // 8.4 MB
    // total ~101 MB

    hipMemsetAsync(rec,    0, NBH*sizeof(double), stream);
    hipMemsetAsync(attrA,  0, NBH*sizeof(double), stream);
    hipMemsetAsync(spkcnt, 0, NBH*sizeof(float),  stream);

    dim3 blk128(128);
    dim3 blk256(256);
    dim3 g_wpf(HH/64, DD/32);    // 32 x 32 = 1024 blocks (4/CU)
    k_wpf<<<g_wpf, blk128, 0, stream>>>(Wp, Wfc, Wpf);
    k_bpf<<<HH/256, blk256, 0, stream>>>(bp, Wfc, bfc, bpf);

    dim3 g_step(HH/64, BB/32);   // 32 x 32 = 1024 blocks (4/CU)
    double* ain  = attrA;
    double* aout = attrB;
    for (int t = 0; t < TT; ++t) {
        k_update <<<g_step, blk128, 0, stream>>>(x, t, Wpf, bpf, rec);
        k_ln     <<<BB,     blk256, 0, stream>>>(rec, gamma, beta, ctx);
        k_gate   <<<g_step, blk128, 0, stream>>>(ctx, rec, Wg, bg, gated);
        k_current<<<g_step, blk128, 0, stream>>>(gated, Wenc, ain, Wrec, benc, brec, aout, spkcnt);
        double* tmp = ain; ain = aout; aout = tmp;
    }
    // final attractor state in `ain`

    dim3 g_ro(OO/64, BB/32);     // 16 x 32 = 512 blocks
    k_readout<<<g_ro, blk128, 0, stream>>>(spkcnt, Wro, bro, out);
    k_d2f<<<NBH/256, blk256, 0, stream>>>(rec, out + (long)BB*OO);
    k_d2f<<<NBH/256, blk256, 0, stream>>>(ain, out + (long)BB*OO + NBH);
}

// Round 6
// 10331.558 us; speedup vs baseline: 1.1439x; 1.1439x over previous
//
#include <hip/hip_runtime.h>
#include <math.h>

// SARABrainCore: 16-step spiking recurrent net, B=1024 T=16 D=1024 H=2048 O=1024.
// R3: inputs fp32, outputs fp32, internals fp64 (spike threshold is chaotic;
// fp64 tracks the fp64 ground truth; absmax 0.0039 vs fp32 JAX ref is spike
// flips from the reference's fp32 rounding, tolerance-accepted). fp32 GEMM is
// NOT safe: a single spike flip changes final attr by 1.0 >> 0.032 threshold.
// R4: GEMM moved to v_mfma_f64_16x16x4_f64 (78.6 TF matrix pipe).
// R5: HW-verified f64 MFMA C/D layout: row=(lane>>4)+4*reg, col=lane&15.
// R4's row=4*(lane>>4)+reg was an involution off (readout passed, rec/attr
// dumps failed). Do NOT revert to the bf16-style mapping.
// R6/R7: 64x64 tile, 4 waves, BK=32 dbuf LDS, 1 barrier/K-tile, reg prefetch
// -> 2 blocks/CU: 548 -> 384 us, MfmaUtil 40 -> 60%.
// R8 FAILED (reverted): BK=16 / 128-thr blocks / 4 blk/CU regressed to 55%
// util -- halving MFMAs-per-barrier doubled per-tile overhead per FLOP.
// Lesson: more MFMA per barrier > more barrier groups.
// R9 (this round): R7 + LDS stride fix. R7's 5.1e7 bank-conflict cycles
// (~22% of CU time) traced to B staging writes: LDBS=66 gives bank-pair
// (4bk+16s+2j) mod 32 -> only multiples of 4, 8 accesses each = 2x floor.
// Odd stride 65 for BOTH As and Bs -> every even bank-pair exactly 4
// accesses (wave64-b64 floor, zero excess); fragment reads stay
// consecutive-double conflict-free. LDS size unchanged -> still 2 blk/CU.
// Fragment layouts (f64 16x16x4): A: row=lane&15, k=lane>>4;
// B: col=lane&15, k=lane>>4; C/D: col=lane&15, row=(lane>>4)+4*reg.

#define BB 1024
#define TT 16
#define DD 1024
#define HH 2048
#define OO 1024

typedef double d4 __attribute__((ext_vector_type(4)));

// ---- element readers ----
struct RdF {                               // fp32 input array
    const float* p; long ld;
    __device__ double operator()(int r, int c) const { return (double)p[(long)r*ld + c]; }
};
struct RdD {                               // fp64 internal array
    const double* p; long ld;
    __device__ double operator()(int r, int c) const { return p[(long)r*ld + c]; }
};
struct RdSum {                             // ctx + rec computed on the fly (exact)
    const double* a; const double* b; long ld;
    __device__ double operator()(int r, int c) const { long i=(long)r*ld+c; return a[i]+b[i]; }
};
struct RdSpk {                             // spike count -> mean (x0.0625 exact)
    const float* p; long ld;
    __device__ double operator()(int r, int c) const { return (double)p[(long)r*ld+c] * 0.0625; }
};

#define LDAS 65                  // As row stride in doubles (64 + 1 pad, ODD)
#define LDBS 65                  // Bs row stride in doubles (64 + 1 pad, ODD)
#define TILE_A (32*LDAS)         // 2080 doubles (BK=32 x M=64+pad, k-major)
#define TILE_B (32*LDBS)         // 2080 doubles (BK=32 x N=64+pad)
#define LDS_DBL (2*(TILE_A + TILE_B))   // 8320 doubles = 66.56 KB

// ---- fp64 MFMA GEMM core: 64x64 tile, 256 thr (4 waves 2x2), BK=32,
// ---- double-buffered LDS, 1 barrier/tile, register prefetch. ----
template<typename AR, typename BR>
__device__ __forceinline__ void gemm_mfma(AR A, BR B, int row0, int col0, int K,
                                          double* __restrict__ S,
                                          d4 acc[2][2])
{
    const int tid  = threadIdx.x;
    const int lane = tid & 63;
    const int wid  = tid >> 6;
    const int wm   = wid >> 1;            // 0..1
    const int wn   = wid & 1;             // 0..1
    const int l15  = lane & 15;
    const int l4   = lane >> 4;           // 0..3 = k within MFMA
    // A staging: 64 rows x 32 k, 8 elems/thread (k-contiguous global reads)
    const int am = tid >> 2, ak = (tid & 3) << 3;
    // B staging: 32 k x 64 cols, 8 elems/thread (col-contiguous global reads)
    const int bk = tid >> 3, bn = (tid & 7) << 3;

    double* A0 = S;
    double* B0 = S + TILE_A;
    double* A1 = S + TILE_A + TILE_B;
    double* B1 = A1 + TILE_A;

    double ar[8], br[8];
    #pragma unroll
    for (int j = 0; j < 8; ++j) ar[j] = A(row0 + am, ak + j);
    #pragma unroll
    for (int j = 0; j < 8; ++j) br[j] = B(bk, col0 + bn + j);

    __syncthreads();                      // prior users of S are done
    #pragma unroll
    for (int j = 0; j < 8; ++j) A0[(ak + j)*LDAS + am] = ar[j];
    #pragma unroll
    for (int j = 0; j < 8; ++j) B0[bk*LDBS + bn + j] = br[j];
    __syncthreads();

    double *cA = A0, *cB = B0, *nA = A1, *nB = B1;
    const int nt = K >> 5;
    for (int t = 0; t < nt; ++t) {
        if (t + 1 < nt) {                 // issue next-tile global loads early
            #pragma unroll
            for (int j = 0; j < 8; ++j) ar[j] = A(row0 + am, (t+1)*32 + ak + j);
            #pragma unroll
            for (int j = 0; j < 8; ++j) br[j] = B((t+1)*32 + bk, col0 + bn + j);
        }
        #pragma unroll
        for (int ks = 0; ks < 8; ++ks) {
            const int kk = ks*4 + l4;
            double a0 = cA[kk*LDAS + wm*32 +      l15];
            double a1 = cA[kk*LDAS + wm*32 + 16 + l15];
            double b0 = cB[kk*LDBS + wn*32 +      l15];
            double b1 = cB[kk*LDBS + wn*32 + 16 + l15];
            acc[0][0] = __builtin_amdgcn_mfma_f64_16x16x4f64(a0, b0, acc[0][0], 0, 0, 0);
            acc[0][1] = __builtin_amdgcn_mfma_f64_16x16x4f64(a0, b1, acc[0][1], 0, 0, 0);
            acc[1][0] = __builtin_amdgcn_mfma_f64_16x16x4f64(a1, b0, acc[1][0], 0, 0, 0);
            acc[1][1] = __builtin_amdgcn_mfma_f64_16x16x4f64(a1, b1, acc[1][1], 0, 0, 0);
        }
        if (t + 1 < nt) {                 // write-late into the other buffer
            #pragma unroll
            for (int j = 0; j < 8; ++j) nA[(ak + j)*LDAS + am] = ar[j];
            #pragma unroll
            for (int j = 0; j < 8; ++j) nB[bk*LDBS + bn + j] = br[j];
            __syncthreads();              // single barrier per K-tile
            double* x;
            x = cA; cA = nA; nA = x;
            x = cB; cB = nB; nB = x;
        }
    }
}

// Output element (i,j,r): row = row0 + wm*32 + i*16 + l4 + 4*r,  (HW-verified)
//                         col = col0 + wn*32 + j*16 + l15.
#define GEMM_EPILOG_VARS                                   \
    const int lane = threadIdx.x & 63;                     \
    const int wid  = threadIdx.x >> 6;                     \
    const int wm   = wid >> 1, wn = wid & 1;               \
    const int l15  = lane & 15, l4 = lane >> 4;

// ---- Wpf = Wp @ Wfc ----
__global__ __launch_bounds__(256) void k_wpf(const float* __restrict__ Wp,
                                             const float* __restrict__ Wfc,
                                             double* __restrict__ Wpf)
{
    __shared__ double S[LDS_DBL];
    d4 acc[2][2] = {};
    int row0 = blockIdx.y*64, col0 = blockIdx.x*64;
    gemm_mfma(RdF{Wp, HH}, RdF{Wfc, HH}, row0, col0, HH, S, acc);
    GEMM_EPILOG_VARS
    #pragma unroll
    for (int i=0;i<2;i++)
      #pragma unroll
      for (int j=0;j<2;j++)
        #pragma unroll
        for (int r=0;r<4;r++) {
            int d = row0 + wm*32 + i*16 + l4 + 4*r;
            int h = col0 + wn*32 + j*16 + l15;
            Wpf[(long)d*HH + h] = acc[i][j][r];
        }
}

// ---- bpf[h] = bp @ Wfc + bfc ----
__global__ __launch_bounds__(256) void k_bpf(const float* __restrict__ bp,
                                             const float* __restrict__ Wfc,
                                             const float* __restrict__ bfc,
                                             double* __restrict__ bpf)
{
    int h = blockIdx.x*256 + threadIdx.x;
    double acc = 0.0;
    for (int k = 0; k < HH; ++k)
        acc = fma((double)bp[k], (double)Wfc[(long)k*HH + h], acc);
    bpf[h] = acc + (double)bfc[h];
}

// ---- update = tanh(x_t @ Wpf + bpf); rec = BETA*rec + (1-BETA)*update ----
__global__ __launch_bounds__(256) void k_update(const float* __restrict__ x, int t,
                                                const double* __restrict__ Wpf,
                                                const double* __restrict__ bpf,
                                                double* __restrict__ rec)
{
    __shared__ double S[LDS_DBL];
    d4 acc[2][2] = {};
    int row0 = blockIdx.y*64, col0 = blockIdx.x*64;
    const float* x_t = x + (long)t*DD;              // row b at x[b*T*D + t*D]
    gemm_mfma(RdF{x_t, (long)TT*DD}, RdD{Wpf, HH}, row0, col0, DD, S, acc);
    GEMM_EPILOG_VARS
    const double BETA = 0.9;
    const double OMB  = 1.0 - BETA;   // Python fp64 semantics
    #pragma unroll
    for (int i=0;i<2;i++)
      #pragma unroll
      for (int j=0;j<2;j++)
        #pragma unroll
        for (int r=0;r<4;r++) {
            int b = row0 + wm*32 + i*16 + l4 + 4*r;
            int h = col0 + wn*32 + j*16 + l15;
            double u = tanh(acc[i][j][r] + bpf[h]);
            long idx = (long)b*HH + h;
            rec[idx] = BETA*rec[idx] + OMB*u;
        }
}

// ---- LayerNorm(rec) -> ctx  (one block per row) ----
__global__ __launch_bounds__(256) void k_ln(const double* __restrict__ rec,
                                            const float* __restrict__ gamma,
                                            const float* __restrict__ beta,
                                            double* __restrict__ ctx)
{
    __shared__ double red[256];
    int b = blockIdx.x, tid = threadIdx.x;
    const double* r = rec + (long)b*HH;
    double s = 0.0;
    for (int h = tid; h < HH; h += 256) s += r[h];
    red[tid] = s; __syncthreads();
    for (int off = 128; off > 0; off >>= 1) {
        if (tid < off) red[tid] += red[tid+off];
        __syncthreads();
    }
    double mean = red[0] / HH;
    __syncthreads();
    double v = 0.0;
    for (int h = tid; h < HH; h += 256) { double d = r[h]-mean; v += d*d; }
    red[tid] = v; __syncthreads();
    for (int off = 128; off > 0; off >>= 1) {
        if (tid < off) red[tid] += red[tid+off];
        __syncthreads();
    }
    double sd = sqrt(red[0] / HH + 1e-5);
    for (int h = tid; h < HH; h += 256) {
        long idx = (long)b*HH + h;
        ctx[idx] = (r[h]-mean)/sd * (double)gamma[h] + (double)beta[h];
    }
}

// ---- g = sigmoid((ctx+rec) @ Wg + bg); gated = g*ctx + (1-g)*rec ----
__global__ __launch_bounds__(256) void k_gate(const double* __restrict__ ctx,
                                              const double* __restrict__ rec,
                                              const float* __restrict__ Wg,
                                              const float* __restrict__ bg,
                                              double* __restrict__ gated)
{
    __shared__ double S[LDS_DBL];
    d4 acc[2][2] = {};
    int row0 = blockIdx.y*64, col0 = blockIdx.x*64;
    gemm_mfma(RdSum{ctx, rec, HH}, RdF{Wg, HH}, row0, col0, HH, S, acc);
    GEMM_EPILOG_VARS
    #pragma unroll
    for (int i=0;i<2;i++)
      #pragma unroll
      for (int j=0;j<2;j++)
        #pragma unroll
        for (int r=0;r<4;r++) {
            int b = row0 + wm*32 + i*16 + l4 + 4*r;
            int h = col0 + wn*32 + j*16 + l15;
            long idx = (long)b*HH + h;
            double g = 1.0/(1.0 + exp(-(acc[i][j][r] + (double)bg[h])));
            gated[idx] = g*ctx[idx] + (1.0-g)*rec[idx];
        }
}

// ---- current = gated@Wenc + attr@Wrec + benc + brec; LIF + spike count ----
__global__ __launch_bounds__(256) void k_current(const double* __restrict__ gated,
                                                 const float* __restrict__ Wenc,
                                                 const double* __restrict__ attr_in,
                                                 const float* __restrict__ Wrec,
                                                 const float* __restrict__ benc,
                                                 const float* __restrict__ brec,
                                                 double* __restrict__ attr_out,
                                                 float* __restrict__ spkcnt)
{
    __shared__ double S[LDS_DBL];
    d4 acc[2][2] = {};
    int row0 = blockIdx.y*64, col0 = blockIdx.x*64;
    gemm_mfma(RdD{gated,   HH}, RdF{Wenc, HH}, row0, col0, HH, S, acc);
    gemm_mfma(RdD{attr_in, HH}, RdF{Wrec, HH}, row0, col0, HH, S, acc);
    GEMM_EPILOG_VARS
    const double TAU = 2.0, THR = 1.0;
    #pragma unroll
    for (int i=0;i<2;i++)
      #pragma unroll
      for (int j=0;j<2;j++)
        #pragma unroll
        for (int r=0;r<4;r++) {
            int b = row0 + wm*32 + i*16 + l4 + 4*r;
            int h = col0 + wn*32 + j*16 + l15;
            long idx = (long)b*HH + h;
            double cur = acc[i][j][r] + (double)benc[h] + (double)brec[h];
            double a   = attr_in[idx];
            double nv  = a + (cur - a)/TAU;
            double sp  = (nv > THR) ? 1.0 : 0.0;
            attr_out[idx] = nv - sp*THR;
            spkcnt[idx] += (float)sp;
        }
}

// ---- out = (spkcnt/16) @ Wro + bro -> fp32 ----
__global__ __launch_bounds__(256) void k_readout(const float* __restrict__ spkcnt,
                                                 const float* __restrict__ Wro,
                                                 const float* __restrict__ bro,
                                                 float* __restrict__ out)
{
    __shared__ double S[LDS_DBL];
    d4 acc[2][2] = {};
    int row0 = blockIdx.y*64, col0 = blockIdx.x*64;
    gemm_mfma(RdSpk{spkcnt, HH}, RdF{Wro, OO}, row0, col0, HH, S, acc);
    GEMM_EPILOG_VARS
    #pragma unroll
    for (int i=0;i<2;i++)
      #pragma unroll
      for (int j=0;j<2;j++)
        #pragma unroll
        for (int r=0;r<4;r++) {
            int b = row0 + wm*32 + i*16 + l4 + 4*r;
            int o = col0 + wn*32 + j*16 + l15;
            out[(long)b*OO + o] = (float)(acc[i][j][r] + (double)bro[o]);
        }
}

__global__ __launch_bounds__(256) void k_d2f(const double* __restrict__ src,
                                             float* __restrict__ dst)
{
    long i = (long)blockIdx.x*256 + threadIdx.x;
    dst[i] = (float)src[i];
}

extern "C" void kernel_launch(void* const* d_in, const int* in_sizes, int n_in,
                              void* d_out, int out_size, void* d_ws, size_t ws_size,
                              hipStream_t stream) {
    const float* x    = (const float*)d_in[0];
    const float* Wp   = (const float*)d_in[1];
    const float* bp   = (const float*)d_in[2];
    const float* Wfc  = (const float*)d_in[3];
    const float* bfc  = (const float*)d_in[4];
    const float* gamma= (const float*)d_in[5];
    const float* beta = (const float*)d_in[6];
    const float* Wg   = (const float*)d_in[7];
    const float* bg   = (const float*)d_in[8];
    const float* Wenc = (const float*)d_in[9];
    const float* benc = (const float*)d_in[10];
    const float* Wrec = (const float*)d_in[11];
    const float* brec = (const float*)d_in[12];
    const float* Wro  = (const float*)d_in[13];
    const float* bro  = (const float*)d_in[14];
    float* out = (float*)d_out;

    const long NBH = (long)BB*HH;     // 2M elems
    char* p = (char*)d_ws;
    double* Wpf   = (double*)p; p += (long)DD*HH*sizeof(double);   // 16.8 MB
    double* bpf   = (double*)p; p += HH*sizeof(double);
    double* rec   = (double*)p; p += NBH*sizeof(double);           // 16.8 MB
    double* attrA = (double*)p; p += NBH*sizeof(double);           // 16.8 MB
    double* attrB = (double*)p; p += NBH*sizeof(double);           // 16.8 MB
    double* ctx   = (double*)p; p += NBH*sizeof(double);           // 16.8 MB
    double* gated = (double*)p; p += NBH*sizeof(double);           // 16.8 MB
    float*  spkcnt= (float*)p;  p += NBH*sizeof(float);            // 8.4 MB
    // total ~101 MB

    hipMemsetAsync(rec,    0, NBH*sizeof(double), stream);
    hipMemsetAsync(attrA,  0, NBH*sizeof(double), stream);
    hipMemsetAsync(spkcnt, 0, NBH*sizeof(float),  stream);

    dim3 blk(256);
    dim3 g_wpf(HH/64, DD/64);    // 32 x 16 = 512 blocks (2/CU)
    k_wpf<<<g_wpf, blk, 0, stream>>>(Wp, Wfc, Wpf);
    k_bpf<<<HH/256, blk, 0, stream>>>(bp, Wfc, bfc, bpf);

    dim3 g_step(HH/64, BB/64);   // 32 x 16 = 512 blocks (2/CU)
    double* ain  = attrA;
    double* aout = attrB;
    for (int t = 0; t < TT; ++t) {
        k_update <<<g_step, blk, 0, stream>>>(x, t, Wpf, bpf, rec);
        k_ln     <<<BB,     blk, 0, stream>>>(rec, gamma, beta, ctx);
        k_gate   <<<g_step, blk, 0, stream>>>(ctx, rec, Wg, bg, gated);
        k_current<<<g_step, blk, 0, stream>>>(gated, Wenc, ain, Wrec, benc, brec, aout, spkcnt);
        double* tmp = ain; ain = aout; aout = tmp;
    }
    // final attractor state in `ain`

    dim3 g_ro(OO/64, BB/64);     // 16 x 16 = 256 blocks
    k_readout<<<g_ro, blk, 0, stream>>>(spkcnt, Wro, bro, out);
    k_d2f<<<NBH/256, blk, 0, stream>>>(rec, out + (long)BB*OO);
    k_d2f<<<NBH/256, blk, 0, stream>>>(ain, out + (long)BB*OO + NBH);
}

// Round 7
// 10021.690 us; speedup vs baseline: 1.1793x; 1.0309x over previous
//
#include <hip/hip_runtime.h>
#include <math.h>

// SARABrainCore: 16-step spiking recurrent net, B=1024 T=16 D=1024 H=2048 O=1024.
// R3: inputs fp32, outputs fp32, internals fp64 (spike threshold is chaotic).
// fp32 GEMM is NOT safe: one spike flip changes final attr by 1.0 >> 0.032 thr.
// R4: GEMM on v_mfma_f64_16x16x4_f64 (78.6 TF matrix pipe).
// R5: HW-verified f64 MFMA C/D layout: row=(lane>>4)+4*reg, col=lane&15.
// (row=4*(lane>>4)+reg is an involution off: readout passes, rec/attr dumps
// fail. Do NOT revert.)
// R6/R7: 64x64 tile, 4 waves, BK=32 dbuf LDS, 1 barrier/K-tile, reg prefetch,
// 2 blk/CU: 548 -> 384 us, MfmaUtil 60%.
// R8 FAILED: BK=16/4blk-CU -> 55% (fewer MFMA per barrier loses).
// R9: odd LDS strides (65): 384 -> 363 us, 65% util. Conflict counter ~5e7 is
// the wave64-b64 4-access/bank FLOOR (not excess) -- LDS conflicts are done.
// R10 (this round): fill the MFMA idle (2700cy/tile/SIMD) three ways:
//  (a) B staged in LDS as RAW FP32 (weights are fp32 inputs; cvt at fragment
//      read is bit-exact). Block LDS 66.5 -> 51.7 KB => 3 blocks/CU capacity.
//      Bs stride 72 f32 (=8 mod 32): reads quarter-waves at banks {0,8,16,24}
//      = b32 floor; row-wise wave writes (float2) = b64 floor.
//      k_update keeps fp64-B core (Wpf is fp64 internal; precision fixed).
//  (b) K-split so grids reach 1024 blocks (3/CU resident): k_current splits
//      by source GEMM (z=0 gated@Wenc -> ctx buf; z=1 attr@Wrec -> aout buf),
//      k_gate splits K into 2x1024 halves. Deterministic combine kernels
//      (k_lif / k_gatefin); partials reuse dead buffers (NO extra ws).
//      Adds ONE fp64 rounding boundary (~1e-16 rel) -- no spike flips.
//      MFMA/barrier stays 32/wave (R8 lesson).
//  (c) XCD-chunked blockIdx swizzle (8x8 chunks; id%8 = XCD) on step GEMMs:
//      cuts the 5x cross-XCD panel duplication (FETCH 165MB vs 33MB ideal).
// Fragment layouts (f64 16x16x4): A: row=lane&15, k=lane>>4;
// B: col=lane&15, k=lane>>4; C/D: col=lane&15, row=(lane>>4)+4*reg.

#define BB 1024
#define TT 16
#define DD 1024
#define HH 2048
#define OO 1024

typedef double d4 __attribute__((ext_vector_type(4)));

// ---- element readers (A operand) ----
struct RdF {                               // fp32 input array
    const float* p; long ld;
    __device__ double operator()(int r, int c) const { return (double)p[(long)r*ld + c]; }
};
struct RdD {                               // fp64 internal array
    const double* p; long ld;
    __device__ double operator()(int r, int c) const { return p[(long)r*ld + c]; }
};
struct RdSum {                             // ctx + rec computed on the fly (exact)
    const double* a; const double* b; long ld;
    __device__ double operator()(int r, int c) const { long i=(long)r*ld+c; return a[i]+b[i]; }
};
struct RdSpk {                             // spike count -> mean (x0.0625 exact)
    const float* p; long ld;
    __device__ double operator()(int r, int c) const { return (double)p[(long)r*ld+c] * 0.0625; }
};

#define LDAS 65                  // As row stride, doubles (64+1, ODD: R9-verified)
#define LDBS 65                  // f64-B Bs row stride, doubles
#define LDBF 72                  // f32-B Bs row stride, floats (=8 mod 32)

// ---------------------------------------------------------------------------
// f32-B core: 64x64 tile, 256 thr (4 waves 2x2), BK=32, dbuf, 1 barrier/tile.
// B staged as raw fp32 (exact); converted to f64 at fragment read.
// LDS: Asd 2*32*65*8 = 33280B + Bsf 2*32*72*4 = 18432B = 51712B -> 3 blk/CU.
// ---------------------------------------------------------------------------
template<typename AR>
__device__ __forceinline__ void gemm32(AR A, const float* __restrict__ Bp, long ldb,
                                       int row0, int col0, int kbase, int K,
                                       double* __restrict__ Asd,
                                       float*  __restrict__ Bsf,
                                       d4 acc[2][2])
{
    const int tid  = threadIdx.x;
    const int lane = tid & 63;
    const int wid  = tid >> 6;
    const int wm   = wid >> 1;            // 0..1
    const int wn   = wid & 1;             // 0..1
    const int l15  = lane & 15;
    const int l4   = lane >> 4;           // 0..3 = k within MFMA
    // A staging: 64 rows x 32 k, 8 doubles/thread (k-contiguous global reads)
    const int am = tid >> 2, ak = (tid & 3) << 3;
    // B staging: wave w stages rows 8w..8w+7; lane: row parity + col pair.
    const int bkb = wid << 3;
    const int brr = lane >> 5;            // 0..1
    const int bc  = (lane & 31) << 1;     // even col

    double* A0 = Asd;           double* A1 = Asd + 32*LDAS;
    float*  B0 = Bsf;           float*  B1 = Bsf + 32*LDBF;

    double ar[8]; float2 br[4];
    #pragma unroll
    for (int j = 0; j < 8; ++j) ar[j] = A(row0 + am, kbase + ak + j);
    #pragma unroll
    for (int j = 0; j < 4; ++j) {
        int rw = bkb + 2*j + brr;
        br[j] = *(const float2*)(Bp + (long)(kbase + rw)*ldb + col0 + bc);
    }
    __syncthreads();                      // prior users of LDS done
    #pragma unroll
    for (int j = 0; j < 8; ++j) A0[(ak + j)*LDAS + am] = ar[j];
    #pragma unroll
    for (int j = 0; j < 4; ++j) {
        int rw = bkb + 2*j + brr;
        *(float2*)(B0 + rw*LDBF + bc) = br[j];
    }
    __syncthreads();

    double *cA = A0, *nA = A1;
    float  *cB = B0, *nB = B1;
    const int nt = K >> 5;
    for (int t = 0; t < nt; ++t) {
        if (t + 1 < nt) {                 // issue next-tile global loads early
            #pragma unroll
            for (int j = 0; j < 8; ++j) ar[j] = A(row0 + am, kbase + (t+1)*32 + ak + j);
            #pragma unroll
            for (int j = 0; j < 4; ++j) {
                int rw = bkb + 2*j + brr;
                br[j] = *(const float2*)(Bp + (long)(kbase + (t+1)*32 + rw)*ldb + col0 + bc);
            }
        }
        #pragma unroll
        for (int ks = 0; ks < 8; ++ks) {
            const int kk = ks*4 + l4;
            double a0 = cA[kk*LDAS + wm*32 +      l15];
            double a1 = cA[kk*LDAS + wm*32 + 16 + l15];
            double b0 = (double)cB[kk*LDBF + wn*32 +      l15];
            double b1 = (double)cB[kk*LDBF + wn*32 + 16 + l15];
            acc[0][0] = __builtin_amdgcn_mfma_f64_16x16x4f64(a0, b0, acc[0][0], 0, 0, 0);
            acc[0][1] = __builtin_amdgcn_mfma_f64_16x16x4f64(a0, b1, acc[0][1], 0, 0, 0);
            acc[1][0] = __builtin_amdgcn_mfma_f64_16x16x4f64(a1, b0, acc[1][0], 0, 0, 0);
            acc[1][1] = __builtin_amdgcn_mfma_f64_16x16x4f64(a1, b1, acc[1][1], 0, 0, 0);
        }
        if (t + 1 < nt) {                 // write-late into the other buffer
            #pragma unroll
            for (int j = 0; j < 8; ++j) nA[(ak + j)*LDAS + am] = ar[j];
            #pragma unroll
            for (int j = 0; j < 4; ++j) {
                int rw = bkb + 2*j + brr;
                *(float2*)(nB + rw*LDBF + bc) = br[j];
            }
            __syncthreads();              // single barrier per K-tile
            double* xd; float* xf;
            xd = cA; cA = nA; nA = xd;
            xf = cB; cB = nB; nB = xf;
        }
    }
}

// ---------------------------------------------------------------------------
// f64-B core (k_update only: B = Wpf fp64). R9 structure, 2 blk/CU.
// ---------------------------------------------------------------------------
template<typename AR, typename BR>
__device__ __forceinline__ void gemm64(AR A, BR B, int row0, int col0, int K,
                                       double* __restrict__ Asd,
                                       double* __restrict__ Bsd,
                                       d4 acc[2][2])
{
    const int tid  = threadIdx.x;
    const int lane = tid & 63;
    const int wid  = tid >> 6;
    const int wm   = wid >> 1;
    const int wn   = wid & 1;
    const int l15  = lane & 15;
    const int l4   = lane >> 4;
    const int am = tid >> 2, ak = (tid & 3) << 3;
    const int bk = tid >> 3, bn = (tid & 7) << 3;

    double* A0 = Asd; double* A1 = Asd + 32*LDAS;
    double* B0 = Bsd; double* B1 = Bsd + 32*LDBS;

    double ar[8], br[8];
    #pragma unroll
    for (int j = 0; j < 8; ++j) ar[j] = A(row0 + am, ak + j);
    #pragma unroll
    for (int j = 0; j < 8; ++j) br[j] = B(bk, col0 + bn + j);

    __syncthreads();
    #pragma unroll
    for (int j = 0; j < 8; ++j) A0[(ak + j)*LDAS + am] = ar[j];
    #pragma unroll
    for (int j = 0; j < 8; ++j) B0[bk*LDBS + bn + j] = br[j];
    __syncthreads();

    double *cA = A0, *cB = B0, *nA = A1, *nB = B1;
    const int nt = K >> 5;
    for (int t = 0; t < nt; ++t) {
        if (t + 1 < nt) {
            #pragma unroll
            for (int j = 0; j < 8; ++j) ar[j] = A(row0 + am, (t+1)*32 + ak + j);
            #pragma unroll
            for (int j = 0; j < 8; ++j) br[j] = B((t+1)*32 + bk, col0 + bn + j);
        }
        #pragma unroll
        for (int ks = 0; ks < 8; ++ks) {
            const int kk = ks*4 + l4;
            double a0 = cA[kk*LDAS + wm*32 +      l15];
            double a1 = cA[kk*LDAS + wm*32 + 16 + l15];
            double b0 = cB[kk*LDBS + wn*32 +      l15];
            double b1 = cB[kk*LDBS + wn*32 + 16 + l15];
            acc[0][0] = __builtin_amdgcn_mfma_f64_16x16x4f64(a0, b0, acc[0][0], 0, 0, 0);
            acc[0][1] = __builtin_amdgcn_mfma_f64_16x16x4f64(a0, b1, acc[0][1], 0, 0, 0);
            acc[1][0] = __builtin_amdgcn_mfma_f64_16x16x4f64(a1, b0, acc[1][0], 0, 0, 0);
            acc[1][1] = __builtin_amdgcn_mfma_f64_16x16x4f64(a1, b1, acc[1][1], 0, 0, 0);
        }
        if (t + 1 < nt) {
            #pragma unroll
            for (int j = 0; j < 8; ++j) nA[(ak + j)*LDAS + am] = ar[j];
            #pragma unroll
            for (int j = 0; j < 8; ++j) nB[bk*LDBS + bn + j] = br[j];
            __syncthreads();
            double* x;
            x = cA; cA = nA; nA = x;
            x = cB; cB = nB; nB = x;
        }
    }
}

// Output element (i,j,r): row = row0 + wm*32 + i*16 + l4 + 4*r,  (HW-verified)
//                         col = col0 + wn*32 + j*16 + l15.
#define GEMM_EPILOG_VARS                                   \
    const int lane = threadIdx.x & 63;                     \
    const int wid  = threadIdx.x >> 6;                     \
    const int wm   = wid >> 1, wn = wid & 1;               \
    const int l15  = lane & 15, l4 = lane >> 4;

// XCD-chunk swizzle for 32x16 grids: blocks with id%8==k form one 8x8
// spatial chunk -> each XCD sees 8 A-strips + 8 B-strips instead of all.
__device__ __forceinline__ void swz3216(int& bx, int& by) {
    int id = bx + (by << 5);
    int k = id & 7, t = id >> 3;            // k = XCD candidate, t = 0..63
    bx = ((k & 3) << 3) + (t & 7);
    by = ((k >> 2) << 3) + (t >> 3);
}

// ---- Wpf = Wp @ Wfc ----
__global__ __launch_bounds__(256, 3) void k_wpf(const float* __restrict__ Wp,
                                                const float* __restrict__ Wfc,
                                                double* __restrict__ Wpf)
{
    __shared__ double Asd[2*32*LDAS];
    __shared__ float  Bsf[2*32*LDBF];
    d4 acc[2][2] = {};
    int bx = blockIdx.x, by = blockIdx.y;
    swz3216(bx, by);
    int row0 = by*64, col0 = bx*64;
    gemm32(RdF{Wp, HH}, Wfc, HH, row0, col0, 0, HH, Asd, Bsf, acc);
    GEMM_EPILOG_VARS
    #pragma unroll
    for (int i=0;i<2;i++)
      #pragma unroll
      for (int j=0;j<2;j++)
        #pragma unroll
        for (int r=0;r<4;r++) {
            int d = row0 + wm*32 + i*16 + l4 + 4*r;
            int h = col0 + wn*32 + j*16 + l15;
            Wpf[(long)d*HH + h] = acc[i][j][r];
        }
}

// ---- bpf[h] = bp @ Wfc + bfc ----
__global__ __launch_bounds__(256) void k_bpf(const float* __restrict__ bp,
                                             const float* __restrict__ Wfc,
                                             const float* __restrict__ bfc,
                                             double* __restrict__ bpf)
{
    int h = blockIdx.x*256 + threadIdx.x;
    double acc = 0.0;
    for (int k = 0; k < HH; ++k)
        acc = fma((double)bp[k], (double)Wfc[(long)k*HH + h], acc);
    bpf[h] = acc + (double)bfc[h];
}

// ---- update = tanh(x_t @ Wpf + bpf); rec = BETA*rec + (1-BETA)*update ----
__global__ __launch_bounds__(256) void k_update(const float* __restrict__ x, int t,
                                                const double* __restrict__ Wpf,
                                                const double* __restrict__ bpf,
                                                double* __restrict__ rec)
{
    __shared__ double Asd[2*32*LDAS];
    __shared__ double Bsd[2*32*LDBS];
    d4 acc[2][2] = {};
    int bx = blockIdx.x, by = blockIdx.y;
    swz3216(bx, by);
    int row0 = by*64, col0 = bx*64;
    const float* x_t = x + (long)t*DD;              // row b at x[b*T*D + t*D]
    gemm64(RdF{x_t, (long)TT*DD}, RdD{Wpf, HH}, row0, col0, DD, Asd, Bsd, acc);
    GEMM_EPILOG_VARS
    const double BETA = 0.9;
    const double OMB  = 1.0 - BETA;   // Python fp64 semantics
    #pragma unroll
    for (int i=0;i<2;i++)
      #pragma unroll
      for (int j=0;j<2;j++)
        #pragma unroll
        for (int r=0;r<4;r++) {
            int b = row0 + wm*32 + i*16 + l4 + 4*r;
            int h = col0 + wn*32 + j*16 + l15;
            double u = tanh(acc[i][j][r] + bpf[h]);
            long idx = (long)b*HH + h;
            rec[idx] = BETA*rec[idx] + OMB*u;
        }
}

// ---- LayerNorm(rec) -> ctx  (one block per row) ----
__global__ __launch_bounds__(256) void k_ln(const double* __restrict__ rec,
                                            const float* __restrict__ gamma,
                                            const float* __restrict__ beta,
                                            double* __restrict__ ctx)
{
    __shared__ double red[256];
    int b = blockIdx.x, tid = threadIdx.x;
    const double* r = rec + (long)b*HH;
    double s = 0.0;
    for (int h = tid; h < HH; h += 256) s += r[h];
    red[tid] = s; __syncthreads();
    for (int off = 128; off > 0; off >>= 1) {
        if (tid < off) red[tid] += red[tid+off];
        __syncthreads();
    }
    double mean = red[0] / HH;
    __syncthreads();
    double v = 0.0;
    for (int h = tid; h < HH; h += 256) { double d = r[h]-mean; v += d*d; }
    red[tid] = v; __syncthreads();
    for (int off = 128; off > 0; off >>= 1) {
        if (tid < off) red[tid] += red[tid+off];
        __syncthreads();
    }
    double sd = sqrt(red[0] / HH + 1e-5);
    for (int h = tid; h < HH; h += 256) {
        long idx = (long)b*HH + h;
        ctx[idx] = (r[h]-mean)/sd * (double)gamma[h] + (double)beta[h];
    }
}

// ---- k_gate_part: z-th K-half of (ctx+rec)@Wg -> partial (p0/p1) ----
__global__ __launch_bounds__(256, 3) void k_gate_part(const double* __restrict__ ctx,
                                                      const double* __restrict__ rec,
                                                      const float* __restrict__ Wg,
                                                      double* __restrict__ p0,
                                                      double* __restrict__ p1)
{
    __shared__ double Asd[2*32*LDAS];
    __shared__ float  Bsf[2*32*LDBF];
    d4 acc[2][2] = {};
    int bx = blockIdx.x, by = blockIdx.y, z = blockIdx.z;
    swz3216(bx, by);
    int row0 = by*64, col0 = bx*64;
    gemm32(RdSum{ctx, rec, HH}, Wg, HH, row0, col0, z*1024, 1024, Asd, Bsf, acc);
    double* P = z ? p1 : p0;
    GEMM_EPILOG_VARS
    #pragma unroll
    for (int i=0;i<2;i++)
      #pragma unroll
      for (int j=0;j<2;j++)
        #pragma unroll
        for (int r=0;r<4;r++) {
            int b = row0 + wm*32 + i*16 + l4 + 4*r;
            int h = col0 + wn*32 + j*16 + l15;
            P[(long)b*HH + h] = acc[i][j][r];
        }
}

// ---- k_gatefin: g = sigmoid(p0+p1+bg); gated = g*ctx + (1-g)*rec ----
// p1 aliases `gated` (read-then-overwrite, same thread/elem: safe).
__global__ __launch_bounds__(256) void k_gatefin(const double* __restrict__ p0,
                                                 const double* __restrict__ ctx,
                                                 const double* __restrict__ rec,
                                                 const float* __restrict__ bg,
                                                 double* __restrict__ gated)
{
    long i = (long)blockIdx.x*256 + threadIdx.x;
    int h = (int)(i & (HH-1));
    double s = p0[i] + gated[i] + (double)bg[h];
    double g = 1.0/(1.0 + exp(-s));
    gated[i] = g*ctx[i] + (1.0-g)*rec[i];
}

// ---- k_current_part: z=0: gated@Wenc -> p0(ctx); z=1: attr@Wrec -> p1(aout) ----
__global__ __launch_bounds__(256, 3) void k_current_part(const double* __restrict__ gated,
                                                         const float* __restrict__ Wenc,
                                                         const double* __restrict__ attr_in,
                                                         const float* __restrict__ Wrec,
                                                         double* __restrict__ p0,
                                                         double* __restrict__ p1)
{
    __shared__ double Asd[2*32*LDAS];
    __shared__ float  Bsf[2*32*LDBF];
    d4 acc[2][2] = {};
    int bx = blockIdx.x, by = blockIdx.y, z = blockIdx.z;
    swz3216(bx, by);
    int row0 = by*64, col0 = bx*64;
    const double* Ap = z ? attr_in : gated;
    const float*  Bp = z ? Wrec    : Wenc;
    double*       Cp = z ? p1      : p0;
    gemm32(RdD{Ap, HH}, Bp, HH, row0, col0, 0, HH, Asd, Bsf, acc);
    GEMM_EPILOG_VARS
    #pragma unroll
    for (int i=0;i<2;i++)
      #pragma unroll
      for (int j=0;j<2;j++)
        #pragma unroll
        for (int r=0;r<4;r++) {
            int b = row0 + wm*32 + i*16 + l4 + 4*r;
            int h = col0 + wn*32 + j*16 + l15;
            Cp[(long)b*HH + h] = acc[i][j][r];
        }
}

// ---- k_lif: cur = p0+p1+benc+brec; LIF + spike count. ----
// p1 aliases attr_out (read-then-overwrite, same thread/elem: safe).
__global__ __launch_bounds__(256) void k_lif(const double* __restrict__ p0,
                                             const double* __restrict__ attr_in,
                                             const float* __restrict__ benc,
                                             const float* __restrict__ brec,
                                             double* __restrict__ attr_out,
                                             float* __restrict__ spkcnt)
{
    long i = (long)blockIdx.x*256 + threadIdx.x;
    int h = (int)(i & (HH-1));
    const double TAU = 2.0, THR = 1.0;
    double cur = p0[i] + attr_out[i] + (double)benc[h] + (double)brec[h];
    double a   = attr_in[i];
    double nv  = a + (cur - a)/TAU;
    double sp  = (nv > THR) ? 1.0 : 0.0;
    attr_out[i] = nv - sp*THR;
    spkcnt[i] += (float)sp;
}

// ---- out = (spkcnt/16) @ Wro + bro -> fp32 ----
__global__ __launch_bounds__(256, 3) void k_readout(const float* __restrict__ spkcnt,
                                                    const float* __restrict__ Wro,
                                                    const float* __restrict__ bro,
                                                    float* __restrict__ out)
{
    __shared__ double Asd[2*32*LDAS];
    __shared__ float  Bsf[2*32*LDBF];
    d4 acc[2][2] = {};
    int row0 = blockIdx.y*64, col0 = blockIdx.x*64;
    gemm32(RdSpk{spkcnt, HH}, Wro, OO, row0, col0, 0, HH, Asd, Bsf, acc);
    GEMM_EPILOG_VARS
    #pragma unroll
    for (int i=0;i<2;i++)
      #pragma unroll
      for (int j=0;j<2;j++)
        #pragma unroll
        for (int r=0;r<4;r++) {
            int b = row0 + wm*32 + i*16 + l4 + 4*r;
            int o = col0 + wn*32 + j*16 + l15;
            out[(long)b*OO + o] = (float)(acc[i][j][r] + (double)bro[o]);
        }
}

__global__ __launch_bounds__(256) void k_d2f(const double* __restrict__ src,
                                             float* __restrict__ dst)
{
    long i = (long)blockIdx.x*256 + threadIdx.x;
    dst[i] = (float)src[i];
}

extern "C" void kernel_launch(void* const* d_in, const int* in_sizes, int n_in,
                              void* d_out, int out_size, void* d_ws, size_t ws_size,
                              hipStream_t stream) {
    const float* x    = (const float*)d_in[0];
    const float* Wp   = (const float*)d_in[1];
    const float* bp   = (const float*)d_in[2];
    const float* Wfc  = (const float*)d_in[3];
    const float* bfc  = (const float*)d_in[4];
    const float* gamma= (const float*)d_in[5];
    const float* beta = (const float*)d_in[6];
    const float* Wg   = (const float*)d_in[7];
    const float* bg   = (const float*)d_in[8];
    const float* Wenc = (const float*)d_in[9];
    const float* benc = (const float*)d_in[10];
    const float* Wrec = (const float*)d_in[11];
    const float* brec = (const float*)d_in[12];
    const float* Wro  = (const float*)d_in[13];
    const float* bro  = (const float*)d_in[14];
    float* out = (float*)d_out;

    const long NBH = (long)BB*HH;     // 2M elems
    char* p = (char*)d_ws;
    double* Wpf   = (double*)p; p += (long)DD*HH*sizeof(double);   // 16.8 MB
    double* bpf   = (double*)p; p += HH*sizeof(double);
    double* rec   = (double*)p; p += NBH*sizeof(double);           // 16.8 MB
    double* attrA = (double*)p; p += NBH*sizeof(double);           // 16.8 MB
    double* attrB = (double*)p; p += NBH*sizeof(double);           // 16.8 MB
    double* ctx   = (double*)p; p += NBH*sizeof(double);           // 16.8 MB
    double* gated = (double*)p; p += NBH*sizeof(double);           // 16.8 MB
    float*  spkcnt= (float*)p;  p += NBH*sizeof(float);            // 8.4 MB
    // total ~101 MB (unchanged vs R9; partials reuse ctx / attr buffers)

    hipMemsetAsync(rec,    0, NBH*sizeof(double), stream);
    hipMemsetAsync(attrA,  0, NBH*sizeof(double), stream);
    hipMemsetAsync(spkcnt, 0, NBH*sizeof(float),  stream);

    dim3 blk(256);
    dim3 g_wpf(HH/64, DD/64);        // 32 x 16 = 512 blocks
    k_wpf<<<g_wpf, blk, 0, stream>>>(Wp, Wfc, Wpf);
    k_bpf<<<HH/256, blk, 0, stream>>>(bp, Wfc, bfc, bpf);

    dim3 g_step (HH/64, BB/64);      // 32 x 16 (k_update)
    dim3 g_split(HH/64, BB/64, 2);   // 32 x 16 x 2 = 1024 blocks (3/CU)
    const int NEW = (int)(NBH/256);  // 8192 elementwise blocks
    double* ain  = attrA;
    double* aout = attrB;
    for (int t = 0; t < TT; ++t) {
        k_update <<<g_step, blk, 0, stream>>>(x, t, Wpf, bpf, rec);
        k_ln     <<<BB,     blk, 0, stream>>>(rec, gamma, beta, ctx);
        // gate: K-split halves -> p0 = aout (scratch), p1 = gated; combine.
        k_gate_part<<<g_split, blk, 0, stream>>>(ctx, rec, Wg, aout, gated);
        k_gatefin  <<<NEW,     blk, 0, stream>>>(aout, ctx, rec, bg, gated);
        // current: source-split -> p0 = ctx (dead), p1 = aout; LIF combine.
        k_current_part<<<g_split, blk, 0, stream>>>(gated, Wenc, ain, Wrec, ctx, aout);
        k_lif         <<<NEW,     blk, 0, stream>>>(ctx, ain, benc, brec, aout, spkcnt);
        double* tmp = ain; ain = aout; aout = tmp;
    }
    // final attractor state in `ain`

    dim3 g_ro(OO/64, BB/64);         // 16 x 16 = 256 blocks
    k_readout<<<g_ro, blk, 0, stream>>>(spkcnt, Wro, bro, out);
    k_d2f<<<NBH/256, blk, 0, stream>>>(rec, out + (long)BB*OO);
    k_d2f<<<NBH/256, blk, 0, stream>>>(ain, out + (long)BB*OO + NBH);
}

// Round 8
// 9857.921 us; speedup vs baseline: 1.1989x; 1.0166x over previous
//
#include <hip/hip_runtime.h>
#include <math.h>

// SARABrainCore: 16-step spiking recurrent net, B=1024 T=16 D=1024 H=2048 O=1024.
// R3: inputs fp32, outputs fp32, internals fp64 (spike threshold is chaotic).
// fp32 GEMM is NOT safe. R4: v_mfma_f64_16x16x4_f64 (78.6 TF pipe).
// R5: HW-verified f64 MFMA C/D layout: row=(lane>>4)+4*reg, col=lane&15.
// (row=4*(lane>>4)+reg is an involution off -- readout passes, rec/attr dumps
// fail. Do NOT revert.)
// R6/R7: 64x64 tile/4 waves/BK=32 dbuf/1 barrier/K-tile: 548->384us, 60% util.
// R8 FAILED: BK=16, 4 blk/CU -> 55% (fewer MFMA per barrier loses).
// R9: odd LDS strides: 363us, 65%. Conflicts at wave64-b64 floor -- done.
// R10: fp32-B staging (51.7KB, 3 blk/CU) + K/source-split (grid 1024) + XCD
// swizzle: 330us, 71% util, conflicts 1.8e7, FETCH 125MB. Total 10.02ms.
// R11 (this round):
//  (a) B DIRECT global->register (no LDS for B): fragment pattern is 16
//      consecutive elems/quarter-wave = coalesced in global already; same
//      cacheline volume as staged (L2-served), bit-identical values.
//      LDS = As only 33.3KB -> 4 blk/CU (16 waves, 4/SIMD); barrier guards
//      only A; B double-buffered in regs, prefetched 1 tile ahead.
//      launch_bounds(256,4) on float-B kernels (~110 VGPR <= 128 cap);
//      k_update (fp64 B, ~145 VGPR) stays (256,2) -- its grid is 2/CU anyway.
//  (b) k_ln -> k_lnstat (mean/sd only, identical reduction tree); ctx
//      recomputed on the fly in gate_part's A-reader and k_gatefin with the
//      exact same fp64 op order ((rec-m)/sd*gamma+beta) -> bitwise identical;
//      removes ctx write + 2 reads (~50MB/step). ctx buffer stays as
//      current_part's p0 scratch.
// Fragment layouts (f64 16x16x4): A: row=lane&15, k=lane>>4;
// B: col=lane&15, k=lane>>4; C/D: col=lane&15, row=(lane>>4)+4*reg.

#define BB 1024
#define TT 16
#define DD 1024
#define HH 2048
#define OO 1024

typedef double d4 __attribute__((ext_vector_type(4)));

// ---- element readers (A operand) ----
struct RdF {                               // fp32 input array
    const float* p; long ld;
    __device__ double operator()(int r, int c) const { return (double)p[(long)r*ld + c]; }
};
struct RdD {                               // fp64 internal array
    const double* p; long ld;
    __device__ double operator()(int r, int c) const { return p[(long)r*ld + c]; }
};
struct RdCR {                              // (ctx + rec) on the fly; ctx from LN stats
    const double* rec; const double* lnm; const double* lnsd;
    const float* gamma; const float* beta; long ld;
    __device__ double operator()(int r, int c) const {
        long i = (long)r*ld + c;
        double rv = rec[i];
        double cv = (rv - lnm[r]) / lnsd[r] * (double)gamma[c] + (double)beta[c];
        return cv + rv;                    // same op order as old k_ln + RdSum
    }
};
struct RdSpk {                             // spike count -> mean (x0.0625 exact)
    const float* p; long ld;
    __device__ double operator()(int r, int c) const { return (double)p[(long)r*ld+c] * 0.0625; }
};

#define LDAS 65                  // As row stride, doubles (64+1, ODD: R9-verified)

// ---------------------------------------------------------------------------
// B-direct GEMM core: 64x64 tile, 256 thr (4 waves 2x2), BK=32.
// A: LDS double-buffered (2*32*65*8 = 33.3KB), 1 barrier/K-tile.
// B: global->register, double-buffered, prefetched 1 tile ahead.
// ---------------------------------------------------------------------------
template<typename AR, typename TB>
__device__ __forceinline__ void gemmBD(AR A, const TB* __restrict__ Bp, long ldb,
                                       int row0, int col0, int kbase, int K,
                                       double* __restrict__ Asd,
                                       d4 acc[2][2])
{
    const int tid  = threadIdx.x;
    const int lane = tid & 63;
    const int wid  = tid >> 6;
    const int wm   = wid >> 1;            // 0..1
    const int wn   = wid & 1;             // 0..1
    const int l15  = lane & 15;
    const int l4   = lane >> 4;           // 0..3 = k within MFMA
    // A staging: 64 rows x 32 k, 8 doubles/thread (k-contiguous global reads)
    const int am = tid >> 2, ak = (tid & 3) << 3;

    double* A0 = Asd;
    double* A1 = Asd + 32*LDAS;

    // per-lane B base: row (kbase + l4), col (col0 + wn*32 + l15)
    const TB* bB = Bp + (long)(kbase + l4)*ldb + col0 + wn*32 + l15;

    double ar[8];
    TB bf[16];                            // [2*ks+j]: row l4+4ks, col +16*j
    #pragma unroll
    for (int j = 0; j < 8; ++j) ar[j] = A(row0 + am, kbase + ak + j);
    #pragma unroll
    for (int ks = 0; ks < 8; ++ks) {
        bf[2*ks+0] = bB[(long)(4*ks)*ldb +  0];
        bf[2*ks+1] = bB[(long)(4*ks)*ldb + 16];
    }
    __syncthreads();                      // prior users of LDS done
    #pragma unroll
    for (int j = 0; j < 8; ++j) A0[(ak + j)*LDAS + am] = ar[j];
    __syncthreads();

    double *cA = A0, *nA = A1;
    const int nt = K >> 5;
    for (int t = 0; t < nt; ++t) {
        TB bn_[16];
        if (t + 1 < nt) {                 // issue next-tile global loads early
            #pragma unroll
            for (int j = 0; j < 8; ++j) ar[j] = A(row0 + am, kbase + (t+1)*32 + ak + j);
            #pragma unroll
            for (int ks = 0; ks < 8; ++ks) {
                bn_[2*ks+0] = bB[(long)((t+1)*32 + 4*ks)*ldb +  0];
                bn_[2*ks+1] = bB[(long)((t+1)*32 + 4*ks)*ldb + 16];
            }
        }
        #pragma unroll
        for (int ks = 0; ks < 8; ++ks) {
            const int kk = ks*4 + l4;
            double a0 = cA[kk*LDAS + wm*32 +      l15];
            double a1 = cA[kk*LDAS + wm*32 + 16 + l15];
            double b0 = (double)bf[2*ks+0];
            double b1 = (double)bf[2*ks+1];
            acc[0][0] = __builtin_amdgcn_mfma_f64_16x16x4f64(a0, b0, acc[0][0], 0, 0, 0);
            acc[0][1] = __builtin_amdgcn_mfma_f64_16x16x4f64(a0, b1, acc[0][1], 0, 0, 0);
            acc[1][0] = __builtin_amdgcn_mfma_f64_16x16x4f64(a1, b0, acc[1][0], 0, 0, 0);
            acc[1][1] = __builtin_amdgcn_mfma_f64_16x16x4f64(a1, b1, acc[1][1], 0, 0, 0);
        }
        if (t + 1 < nt) {                 // write-late A into the other buffer
            #pragma unroll
            for (int j = 0; j < 8; ++j) nA[(ak + j)*LDAS + am] = ar[j];
            __syncthreads();              // single barrier per K-tile (A only)
            double* x = cA; cA = nA; nA = x;
            #pragma unroll
            for (int q = 0; q < 16; ++q) bf[q] = bn_[q];
        }
    }
}

// Output element (i,j,r): row = row0 + wm*32 + i*16 + l4 + 4*r,  (HW-verified)
//                         col = col0 + wn*32 + j*16 + l15.
#define GEMM_EPILOG_VARS                                   \
    const int lane = threadIdx.x & 63;                     \
    const int wid  = threadIdx.x >> 6;                     \
    const int wm   = wid >> 1, wn = wid & 1;               \
    const int l15  = lane & 15, l4 = lane >> 4;

// XCD-chunk swizzle for 32x16 grids: blocks with id%8==k form one 8x8
// spatial chunk -> each XCD sees 8 A-strips + 8 B-strips instead of all.
__device__ __forceinline__ void swz3216(int& bx, int& by) {
    int id = bx + (by << 5);
    int k = id & 7, t = id >> 3;            // k = XCD candidate, t = 0..63
    bx = ((k & 3) << 3) + (t & 7);
    by = ((k >> 2) << 3) + (t >> 3);
}

// ---- Wpf = Wp @ Wfc ----
__global__ __launch_bounds__(256, 4) void k_wpf(const float* __restrict__ Wp,
                                                const float* __restrict__ Wfc,
                                                double* __restrict__ Wpf)
{
    __shared__ double Asd[2*32*LDAS];
    d4 acc[2][2] = {};
    int bx = blockIdx.x, by = blockIdx.y;
    swz3216(bx, by);
    int row0 = by*64, col0 = bx*64;
    gemmBD(RdF{Wp, HH}, Wfc, HH, row0, col0, 0, HH, Asd, acc);
    GEMM_EPILOG_VARS
    #pragma unroll
    for (int i=0;i<2;i++)
      #pragma unroll
      for (int j=0;j<2;j++)
        #pragma unroll
        for (int r=0;r<4;r++) {
            int d = row0 + wm*32 + i*16 + l4 + 4*r;
            int h = col0 + wn*32 + j*16 + l15;
            Wpf[(long)d*HH + h] = acc[i][j][r];
        }
}

// ---- bpf[h] = bp @ Wfc + bfc ----
__global__ __launch_bounds__(256) void k_bpf(const float* __restrict__ bp,
                                             const float* __restrict__ Wfc,
                                             const float* __restrict__ bfc,
                                             double* __restrict__ bpf)
{
    int h = blockIdx.x*256 + threadIdx.x;
    double acc = 0.0;
    for (int k = 0; k < HH; ++k)
        acc = fma((double)bp[k], (double)Wfc[(long)k*HH + h], acc);
    bpf[h] = acc + (double)bfc[h];
}

// ---- update = tanh(x_t @ Wpf + bpf); rec = BETA*rec + (1-BETA)*update ----
// fp64-B direct needs ~145 VGPR -> bounds(256,2); grid 512 = 2/CU anyway.
__global__ __launch_bounds__(256, 2) void k_update(const float* __restrict__ x, int t,
                                                   const double* __restrict__ Wpf,
                                                   const double* __restrict__ bpf,
                                                   double* __restrict__ rec)
{
    __shared__ double Asd[2*32*LDAS];
    d4 acc[2][2] = {};
    int bx = blockIdx.x, by = blockIdx.y;
    swz3216(bx, by);
    int row0 = by*64, col0 = bx*64;
    const float* x_t = x + (long)t*DD;              // row b at x[b*T*D + t*D]
    gemmBD(RdF{x_t, (long)TT*DD}, Wpf, (long)HH, row0, col0, 0, DD, Asd, acc);
    GEMM_EPILOG_VARS
    const double BETA = 0.9;
    const double OMB  = 1.0 - BETA;   // Python fp64 semantics
    #pragma unroll
    for (int i=0;i<2;i++)
      #pragma unroll
      for (int j=0;j<2;j++)
        #pragma unroll
        for (int r=0;r<4;r++) {
            int b = row0 + wm*32 + i*16 + l4 + 4*r;
            int h = col0 + wn*32 + j*16 + l15;
            double u = tanh(acc[i][j][r] + bpf[h]);
            long idx = (long)b*HH + h;
            rec[idx] = BETA*rec[idx] + OMB*u;
        }
}

// ---- LN stats only: mean[b], sd[b] (identical reduction tree to old k_ln) ----
__global__ __launch_bounds__(256) void k_lnstat(const double* __restrict__ rec,
                                                double* __restrict__ lnm,
                                                double* __restrict__ lnsd)
{
    __shared__ double red[256];
    int b = blockIdx.x, tid = threadIdx.x;
    const double* r = rec + (long)b*HH;
    double s = 0.0;
    for (int h = tid; h < HH; h += 256) s += r[h];
    red[tid] = s; __syncthreads();
    for (int off = 128; off > 0; off >>= 1) {
        if (tid < off) red[tid] += red[tid+off];
        __syncthreads();
    }
    double mean = red[0] / HH;
    __syncthreads();
    double v = 0.0;
    for (int h = tid; h < HH; h += 256) { double d = r[h]-mean; v += d*d; }
    red[tid] = v; __syncthreads();
    for (int off = 128; off > 0; off >>= 1) {
        if (tid < off) red[tid] += red[tid+off];
        __syncthreads();
    }
    if (tid == 0) {
        lnm[b]  = mean;
        lnsd[b] = sqrt(red[0] / HH + 1e-5);
    }
}

// ---- k_gate_part: z-th K-half of (ctx+rec)@Wg -> partial (p0/p1) ----
__global__ __launch_bounds__(256, 4) void k_gate_part(const double* __restrict__ rec,
                                                      const double* __restrict__ lnm,
                                                      const double* __restrict__ lnsd,
                                                      const float* __restrict__ gamma,
                                                      const float* __restrict__ beta,
                                                      const float* __restrict__ Wg,
                                                      double* __restrict__ p0,
                                                      double* __restrict__ p1)
{
    __shared__ double Asd[2*32*LDAS];
    d4 acc[2][2] = {};
    int bx = blockIdx.x, by = blockIdx.y, z = blockIdx.z;
    swz3216(bx, by);
    int row0 = by*64, col0 = bx*64;
    gemmBD(RdCR{rec, lnm, lnsd, gamma, beta, HH}, Wg, (long)HH,
           row0, col0, z*1024, 1024, Asd, acc);
    double* P = z ? p1 : p0;
    GEMM_EPILOG_VARS
    #pragma unroll
    for (int i=0;i<2;i++)
      #pragma unroll
      for (int j=0;j<2;j++)
        #pragma unroll
        for (int r=0;r<4;r++) {
            int b = row0 + wm*32 + i*16 + l4 + 4*r;
            int h = col0 + wn*32 + j*16 + l15;
            P[(long)b*HH + h] = acc[i][j][r];
        }
}

// ---- k_gatefin: g = sigmoid(p0+p1+bg); gated = g*ctx + (1-g)*rec ----
// p1 aliases `gated` (read-then-overwrite, same thread/elem: safe).
// ctx recomputed from rec + LN stats (bitwise = old k_ln output).
__global__ __launch_bounds__(256) void k_gatefin(const double* __restrict__ p0,
                                                 const double* __restrict__ rec,
                                                 const double* __restrict__ lnm,
                                                 const double* __restrict__ lnsd,
                                                 const float* __restrict__ gamma,
                                                 const float* __restrict__ beta,
                                                 const float* __restrict__ bg,
                                                 double* __restrict__ gated)
{
    long i = (long)blockIdx.x*256 + threadIdx.x;
    int h   = (int)(i & (HH-1));
    int row = (int)(i >> 11);                 // HH = 2048
    double rv = rec[i];
    double cv = (rv - lnm[row]) / lnsd[row] * (double)gamma[h] + (double)beta[h];
    double s = p0[i] + gated[i] + (double)bg[h];
    double g = 1.0/(1.0 + exp(-s));
    gated[i] = g*cv + (1.0-g)*rv;
}

// ---- k_current_part: z=0: gated@Wenc -> p0(ctx); z=1: attr@Wrec -> p1(aout) ----
__global__ __launch_bounds__(256, 4) void k_current_part(const double* __restrict__ gated,
                                                         const float* __restrict__ Wenc,
                                                         const double* __restrict__ attr_in,
                                                         const float* __restrict__ Wrec,
                                                         double* __restrict__ p0,
                                                         double* __restrict__ p1)
{
    __shared__ double Asd[2*32*LDAS];
    d4 acc[2][2] = {};
    int bx = blockIdx.x, by = blockIdx.y, z = blockIdx.z;
    swz3216(bx, by);
    int row0 = by*64, col0 = bx*64;
    const double* Ap = z ? attr_in : gated;
    const float*  Bp = z ? Wrec    : Wenc;
    double*       Cp = z ? p1      : p0;
    gemmBD(RdD{Ap, HH}, Bp, (long)HH, row0, col0, 0, HH, Asd, acc);
    GEMM_EPILOG_VARS
    #pragma unroll
    for (int i=0;i<2;i++)
      #pragma unroll
      for (int j=0;j<2;j++)
        #pragma unroll
        for (int r=0;r<4;r++) {
            int b = row0 + wm*32 + i*16 + l4 + 4*r;
            int h = col0 + wn*32 + j*16 + l15;
            Cp[(long)b*HH + h] = acc[i][j][r];
        }
}

// ---- k_lif: cur = p0+p1+benc+brec; LIF + spike count. ----
// p1 aliases attr_out (read-then-overwrite, same thread/elem: safe).
__global__ __launch_bounds__(256) void k_lif(const double* __restrict__ p0,
                                             const double* __restrict__ attr_in,
                                             const float* __restrict__ benc,
                                             const float* __restrict__ brec,
                                             double* __restrict__ attr_out,
                                             float* __restrict__ spkcnt)
{
    long i = (long)blockIdx.x*256 + threadIdx.x;
    int h = (int)(i & (HH-1));
    const double TAU = 2.0, THR = 1.0;
    double cur = p0[i] + attr_out[i] + (double)benc[h] + (double)brec[h];
    double a   = attr_in[i];
    double nv  = a + (cur - a)/TAU;
    double sp  = (nv > THR) ? 1.0 : 0.0;
    attr_out[i] = nv - sp*THR;
    spkcnt[i] += (float)sp;
}

// ---- out = (spkcnt/16) @ Wro + bro -> fp32 ----
__global__ __launch_bounds__(256, 4) void k_readout(const float* __restrict__ spkcnt,
                                                    const float* __restrict__ Wro,
                                                    const float* __restrict__ bro,
                                                    float* __restrict__ out)
{
    __shared__ double Asd[2*32*LDAS];
    d4 acc[2][2] = {};
    int row0 = blockIdx.y*64, col0 = blockIdx.x*64;
    gemmBD(RdSpk{spkcnt, HH}, Wro, (long)OO, row0, col0, 0, HH, Asd, acc);
    GEMM_EPILOG_VARS
    #pragma unroll
    for (int i=0;i<2;i++)
      #pragma unroll
      for (int j=0;j<2;j++)
        #pragma unroll
        for (int r=0;r<4;r++) {
            int b = row0 + wm*32 + i*16 + l4 + 4*r;
            int o = col0 + wn*32 + j*16 + l15;
            out[(long)b*OO + o] = (float)(acc[i][j][r] + (double)bro[o]);
        }
}

__global__ __launch_bounds__(256) void k_d2f(const double* __restrict__ src,
                                             float* __restrict__ dst)
{
    long i = (long)blockIdx.x*256 + threadIdx.x;
    dst[i] = (float)src[i];
}

extern "C" void kernel_launch(void* const* d_in, const int* in_sizes, int n_in,
                              void* d_out, int out_size, void* d_ws, size_t ws_size,
                              hipStream_t stream) {
    const float* x    = (const float*)d_in[0];
    const float* Wp   = (const float*)d_in[1];
    const float* bp   = (const float*)d_in[2];
    const float* Wfc  = (const float*)d_in[3];
    const float* bfc  = (const float*)d_in[4];
    const float* gamma= (const float*)d_in[5];
    const float* beta = (const float*)d_in[6];
    const float* Wg   = (const float*)d_in[7];
    const float* bg   = (const float*)d_in[8];
    const float* Wenc = (const float*)d_in[9];
    const float* benc = (const float*)d_in[10];
    const float* Wrec = (const float*)d_in[11];
    const float* brec = (const float*)d_in[12];
    const float* Wro  = (const float*)d_in[13];
    const float* bro  = (const float*)d_in[14];
    float* out = (float*)d_out;

    const long NBH = (long)BB*HH;     // 2M elems
    char* p = (char*)d_ws;
    double* Wpf   = (double*)p; p += (long)DD*HH*sizeof(double);   // 16.8 MB
    double* bpf   = (double*)p; p += HH*sizeof(double);
    double* rec   = (double*)p; p += NBH*sizeof(double);           // 16.8 MB
    double* attrA = (double*)p; p += NBH*sizeof(double);           // 16.8 MB
    double* attrB = (double*)p; p += NBH*sizeof(double);           // 16.8 MB
    double* ctx   = (double*)p; p += NBH*sizeof(double);           // 16.8 MB (scratch p0)
    double* gated = (double*)p; p += NBH*sizeof(double);           // 16.8 MB
    float*  spkcnt= (float*)p;  p += NBH*sizeof(float);            // 8.4 MB
    double* lnm   = (double*)p; p += BB*sizeof(double);            // 8 KB
    double* lnsd  = (double*)p; p += BB*sizeof(double);            // 8 KB
    // total ~101 MB

    hipMemsetAsync(rec,    0, NBH*sizeof(double), stream);
    hipMemsetAsync(attrA,  0, NBH*sizeof(double), stream);
    hipMemsetAsync(spkcnt, 0, NBH*sizeof(float),  stream);

    dim3 blk(256);
    dim3 g_wpf(HH/64, DD/64);        // 32 x 16 = 512 blocks
    k_wpf<<<g_wpf, blk, 0, stream>>>(Wp, Wfc, Wpf);
    k_bpf<<<HH/256, blk, 0, stream>>>(bp, Wfc, bfc, bpf);

    dim3 g_step (HH/64, BB/64);      // 32 x 16 (k_update)
    dim3 g_split(HH/64, BB/64, 2);   // 32 x 16 x 2 = 1024 blocks (4/CU)
    const int NEW = (int)(NBH/256);  // 8192 elementwise blocks
    double* ain  = attrA;
    double* aout = attrB;
    for (int t = 0; t < TT; ++t) {
        k_update <<<g_step, blk, 0, stream>>>(x, t, Wpf, bpf, rec);
        k_lnstat <<<BB,     blk, 0, stream>>>(rec, lnm, lnsd);
        // gate: K-split halves -> p0 = aout (scratch), p1 = gated; combine.
        k_gate_part<<<g_split, blk, 0, stream>>>(rec, lnm, lnsd, gamma, beta, Wg, aout, gated);
        k_gatefin  <<<NEW,     blk, 0, stream>>>(aout, rec, lnm, lnsd, gamma, beta, bg, gated);
        // current: source-split -> p0 = ctx (scratch), p1 = aout; LIF combine.
        k_current_part<<<g_split, blk, 0, stream>>>(gated, Wenc, ain, Wrec, ctx, aout);
        k_lif         <<<NEW,     blk, 0, stream>>>(ctx, ain, benc, brec, aout, spkcnt);
        double* tmp = ain; ain = aout; aout = tmp;
    }
    // final attractor state in `ain`

    dim3 g_ro(OO/64, BB/64);         // 16 x 16 = 256 blocks
    k_readout<<<g_ro, blk, 0, stream>>>(spkcnt, Wro, bro, out);
    k_d2f<<<NBH/256, blk, 0, stream>>>(rec, out + (long)BB*OO);
    k_d2f<<<NBH/256, blk, 0, stream>>>(ain, out + (long)BB*OO + NBH);
}